// Round 1
// 954.423 us; speedup vs baseline: 1.0238x; 1.0238x over previous
//
#include <hip/hip_runtime.h>
#include <stdint.h>

#define HW 262144      // 512*512
#define LDIM 512

typedef __bf16 bf16x8 __attribute__((ext_vector_type(8)));
typedef float f32x4 __attribute__((ext_vector_type(4)));
typedef short s16x8 __attribute__((ext_vector_type(8)));
typedef short s16x4 __attribute__((ext_vector_type(4)));

__device__ __forceinline__ unsigned short f2bf(float f) {
  union { float f; unsigned u; } v; v.f = f;
  unsigned r = v.u + 0x7fffu + ((v.u >> 16) & 1u);
  return (unsigned short)(r >> 16);
}

__device__ __forceinline__ float bf2f(short s) {
  union { unsigned u; float f; } v;
  v.u = ((unsigned)(unsigned short)s) << 16;
  return v.f;
}

__device__ __forceinline__ s16x8 pack_bf8(float4 a, float4 b) {
  s16x8 r;
  r[0] = (short)f2bf(a.x); r[1] = (short)f2bf(a.y);
  r[2] = (short)f2bf(a.z); r[3] = (short)f2bf(a.w);
  r[4] = (short)f2bf(b.x); r[5] = (short)f2bf(b.y);
  r[6] = (short)f2bf(b.z); r[7] = (short)f2bf(b.w);
  return r;
}

__device__ __forceinline__ f32x4 mfma16(bf16x8 a, bf16x8 b, f32x4 c) {
  return __builtin_amdgcn_mfma_f32_16x16x32_bf16(a, b, c, 0, 0, 0);
}

// async global->LDS, 16B per lane, LDS dest = wave-uniform base + lane*16
__device__ __forceinline__ void gl_lds16(const short* g, short* l) {
  __builtin_amdgcn_global_load_lds(
      (const __attribute__((address_space(1))) void*)g,
      (__attribute__((address_space(3))) void*)l, 16, 0, 0);
}

// ---------------------------------------------------------------------------
// cast x (fp32) -> xb bf16 [c][h][w] and xt bf16 [c][w][h] (64x64 LDS transpose)
// grid: (8 wtile, 8 htile, nb*64)
// ---------------------------------------------------------------------------
__global__ __launch_bounds__(256) void cast_k(const float* __restrict__ x,
                                              short* __restrict__ xb,
                                              short* __restrict__ xt) {
  __shared__ short L[64][72];
  int z = blockIdx.z;
  int h0 = blockIdx.y * 64, w0 = blockIdx.x * 64;
  int tid = threadIdx.x;
  size_t base = (size_t)z * HW;
  int hl = tid >> 4;          // 0..15
  int wl = (tid & 15) * 4;    // 0..60
#pragma unroll
  for (int it = 0; it < 4; ++it) {
    int h = h0 + hl + it * 16;
    float4 v = *(const float4*)(x + base + (size_t)h * 512 + w0 + wl);
    s16x4 b;
    b[0] = (short)f2bf(v.x); b[1] = (short)f2bf(v.y);
    b[2] = (short)f2bf(v.z); b[3] = (short)f2bf(v.w);
    *(s16x4*)(xb + base + (size_t)h * 512 + w0 + wl) = b;
    L[wl + 0][hl + it * 16] = b[0];
    L[wl + 1][hl + it * 16] = b[1];
    L[wl + 2][hl + it * 16] = b[2];
    L[wl + 3][hl + it * 16] = b[3];
  }
  __syncthreads();
#pragma unroll
  for (int it = 0; it < 4; ++it) {
    int w = hl + it * 16;
    s16x4 v = *(const s16x4*)(&L[w][wl]);   // wl is h-offset here
    *(s16x4*)(xt + base + (size_t)(w0 + w) * 512 + h0 + wl) = v;
  }
}

// ---------------------------------------------------------------------------
// Fused QKV conv from bf16 xb: 128 positions x 96 out channels
// co 0..7=Qt, 8..15=Kt, 16..23=Qf, 24..31=Kf (biased); 32..95=Vf (no bias,
// fv bias is folded into the gemm_tf epilogue constant).
// ---------------------------------------------------------------------------
__global__ __launch_bounds__(256, 2) void conv_qkvf_k(
    const short* __restrict__ xb,
    const float* __restrict__ tqw, const float* __restrict__ tqb,
    const float* __restrict__ tkw, const float* __restrict__ tkb,
    const float* __restrict__ fqw, const float* __restrict__ fqb,
    const float* __restrict__ fkw, const float* __restrict__ fkb,
    const float* __restrict__ fvw,
    short* __restrict__ QT, short* __restrict__ KT,
    short* __restrict__ QF, short* __restrict__ KF,
    short* __restrict__ Vf) {
  __shared__ __align__(16) short As[128 * 72];   // x^T tile [p][ci]
  __shared__ __align__(16) short Ws[96 * 72];    // weights [co][ci]
  __shared__ float bia[32];
  int tid = threadIdx.x;
  int n = blockIdx.x >> 11;
  int p0 = (blockIdx.x & 2047) << 7;
#pragma unroll
  for (int i = 0; i < 3; ++i) {
    int idx = i * 256 + tid;                 // 0..767
    int co = idx >> 3, k0 = (idx & 7) * 8;
    const float* wrow = (co < 8)  ? tqw + co * 64
                      : (co < 16) ? tkw + (co - 8) * 64
                      : (co < 24) ? fqw + (co - 16) * 64
                      : (co < 32) ? fkw + (co - 24) * 64
                                  : fvw + (co - 32) * 64;
    float4 f0 = *(const float4*)(wrow + k0);
    float4 f1 = *(const float4*)(wrow + k0 + 4);
    *(s16x8*)(Ws + co * 72 + k0) = pack_bf8(f0, f1);
  }
  if (tid < 32) {
    const float* bsrc = (tid < 8) ? tqb : (tid < 16) ? tkb : (tid < 24) ? fqb : fkb;
    bia[tid] = bsrc[tid & 7];
  }
  {
    int mp = (tid & 31) * 4, k0 = (tid >> 5) * 8;
    const short* sp = xb + ((size_t)(n * 64 + k0)) * HW + p0 + mp;
    s16x8 t0, t1, t2, t3;
#pragma unroll
    for (int j = 0; j < 8; ++j) {
      s16x4 vv = *(const s16x4*)(sp + (size_t)j * HW);
      t0[j] = vv[0]; t1[j] = vv[1]; t2[j] = vv[2]; t3[j] = vv[3];
    }
    *(s16x8*)(As + (mp + 0) * 72 + k0) = t0;
    *(s16x8*)(As + (mp + 1) * 72 + k0) = t1;
    *(s16x8*)(As + (mp + 2) * 72 + k0) = t2;
    *(s16x8*)(As + (mp + 3) * 72 + k0) = t3;
  }
  __syncthreads();
  int lane = tid & 63, wv = tid >> 6, fr = lane & 15, q = lane >> 4;
  int wm = wv * 32;
  f32x4 acc[2][6];
#pragma unroll
  for (int mi = 0; mi < 2; ++mi)
#pragma unroll
    for (int ni = 0; ni < 6; ++ni) acc[mi][ni] = (f32x4){0.f, 0.f, 0.f, 0.f};
#pragma unroll
  for (int ks = 0; ks < 2; ++ks) {
    bf16x8 af[2], bw[6];
#pragma unroll
    for (int mi = 0; mi < 2; ++mi)
      af[mi] = *(const bf16x8*)(As + (wm + mi * 16 + fr) * 72 + ks * 32 + q * 8);
#pragma unroll
    for (int ni = 0; ni < 6; ++ni)
      bw[ni] = *(const bf16x8*)(Ws + (ni * 16 + fr) * 72 + ks * 32 + q * 8);
#pragma unroll
    for (int mi = 0; mi < 2; ++mi)
#pragma unroll
      for (int ni = 0; ni < 6; ++ni)
        acc[mi][ni] = mfma16(af[mi], bw[ni], acc[mi][ni]);
  }
#pragma unroll
  for (int mi = 0; mi < 2; ++mi)
#pragma unroll
    for (int ni = 0; ni < 6; ++ni) {
      int pl = wm + mi * 16 + q * 4;
      int co = ni * 16 + fr;
      float b = 0.f;
      short* dst;
      if (co < 32) {
        b = bia[co];
        short* dd = (co < 8) ? QT : (co < 16) ? KT : (co < 24) ? QF : KF;
        dst = dd + ((size_t)(n * 8 + (co & 7))) * HW;
      } else {
        dst = Vf + ((size_t)(n * 64 + (co - 32))) * HW;
      }
      s16x4 sv;
#pragma unroll
      for (int r = 0; r < 4; ++r) sv[r] = (short)f2bf(acc[mi][ni][r] + b);
      *(s16x4*)(dst + p0 + pl) = sv;
    }
}

// ---------------------------------------------------------------------------
// V conv, 64 out channels, no bias. Used in-place on xt -> VtT (each block
// reads exactly the 128-position tile it overwrites; all global reads complete
// before __syncthreads, writes happen after => safe).
// ---------------------------------------------------------------------------
__global__ __launch_bounds__(256, 2) void conv_v_k(
    const short* xin, const float* __restrict__ w64, short* vout) {
  __shared__ __align__(16) short As[128 * 72];
  __shared__ __align__(16) short Ws[64 * 72];
  int tid = threadIdx.x;
  int n = blockIdx.x >> 11;
  int p0 = (blockIdx.x & 2047) << 7;
#pragma unroll
  for (int i = 0; i < 2; ++i) {
    int idx = i * 256 + tid;                 // 0..511
    int co = idx >> 3, k0 = (idx & 7) * 8;
    const float* wrow = w64 + co * 64;
    float4 f0 = *(const float4*)(wrow + k0);
    float4 f1 = *(const float4*)(wrow + k0 + 4);
    *(s16x8*)(Ws + co * 72 + k0) = pack_bf8(f0, f1);
  }
  {
    int mp = (tid & 31) * 4, k0 = (tid >> 5) * 8;
    const short* sp = xin + ((size_t)(n * 64 + k0)) * HW + p0 + mp;
    s16x8 t0, t1, t2, t3;
#pragma unroll
    for (int j = 0; j < 8; ++j) {
      s16x4 vv = *(const s16x4*)(sp + (size_t)j * HW);
      t0[j] = vv[0]; t1[j] = vv[1]; t2[j] = vv[2]; t3[j] = vv[3];
    }
    *(s16x8*)(As + (mp + 0) * 72 + k0) = t0;
    *(s16x8*)(As + (mp + 1) * 72 + k0) = t1;
    *(s16x8*)(As + (mp + 2) * 72 + k0) = t2;
    *(s16x8*)(As + (mp + 3) * 72 + k0) = t3;
  }
  __syncthreads();
  int lane = tid & 63, wv = tid >> 6, fr = lane & 15, q = lane >> 4;
  int wm = wv * 32;
  f32x4 acc[2][4];
#pragma unroll
  for (int mi = 0; mi < 2; ++mi)
#pragma unroll
    for (int ni = 0; ni < 4; ++ni) acc[mi][ni] = (f32x4){0.f, 0.f, 0.f, 0.f};
#pragma unroll
  for (int ks = 0; ks < 2; ++ks) {
    bf16x8 af[2], bw[4];
#pragma unroll
    for (int mi = 0; mi < 2; ++mi)
      af[mi] = *(const bf16x8*)(As + (wm + mi * 16 + fr) * 72 + ks * 32 + q * 8);
#pragma unroll
    for (int ni = 0; ni < 4; ++ni)
      bw[ni] = *(const bf16x8*)(Ws + (ni * 16 + fr) * 72 + ks * 32 + q * 8);
#pragma unroll
    for (int mi = 0; mi < 2; ++mi)
#pragma unroll
      for (int ni = 0; ni < 4; ++ni)
        acc[mi][ni] = mfma16(af[mi], bw[ni], acc[mi][ni]);
  }
#pragma unroll
  for (int mi = 0; mi < 2; ++mi)
#pragma unroll
    for (int ni = 0; ni < 4; ++ni) {
      int pl = wm + mi * 16 + q * 4;
      int co = ni * 16 + fr;
      short* d = vout + ((size_t)(n * 64 + co)) * HW + p0 + pl;
      s16x4 sv;
#pragma unroll
      for (int r = 0; r < 4; ++r) sv[r] = (short)f2bf(acc[mi][ni][r]);
      *(s16x4*)d = sv;
    }
}

// ---------------------------------------------------------------------------
// Async GEMM (m97 structure): C[m][n] = sum_k A[m][k]*B[n][k], K=512, ld=512,
// both operands K-contiguous bf16. 128x128 tile, BK=32, unpadded [128][32]
// LDS, staged via global_load_lds dwordx4. (energy_t partials, fp32 out)
// ---------------------------------------------------------------------------
template<bool OBF>
__global__ __launch_bounds__(256, 4) void gemm_a(
    const short* __restrict__ A0, long az, int zshA,
    const short* __restrict__ B0, long bz, int zshB,
    void* __restrict__ C0, long cz) {
  __shared__ __align__(16) short As[128 * 32];
  __shared__ __align__(16) short Bs[128 * 32];
  int tid = threadIdx.x;
  int z = blockIdx.z;
  int m0g = blockIdx.y * 128, n0g = blockIdx.x * 128;
  const short* Abz = A0 + (size_t)(z >> zshA) * (size_t)az;
  const short* Bbz = B0 + (size_t)(z >> zshB) * (size_t)bz;
  int lane = tid & 63, wv = tid >> 6;
  int wm = (wv >> 1) * 64, wn = (wv & 1) * 64;
  int fr = lane & 15, q = lane >> 4;

  int srow = lane >> 2;         // 0..15
  int sch = (lane & 3) * 8;     // short offset within row
  const short* ga0 = Abz + (size_t)(m0g + wv * 32 + srow) * 512 + sch;
  const short* ga1 = ga0 + 16 * 512;
  const short* gb0 = Bbz + (size_t)(n0g + wv * 32 + srow) * 512 + sch;
  const short* gb1 = gb0 + 16 * 512;
  short* la0 = As + (wv * 32) * 32;
  short* la1 = As + (wv * 32 + 16) * 32;
  short* lb0 = Bs + (wv * 32) * 32;
  short* lb1 = Bs + (wv * 32 + 16) * 32;

  f32x4 acc[4][4];
#pragma unroll
  for (int mi = 0; mi < 4; ++mi)
#pragma unroll
    for (int ni = 0; ni < 4; ++ni) acc[mi][ni] = (f32x4){0.f, 0.f, 0.f, 0.f};

  for (int kk = 0; kk < 512; kk += 32) {
    gl_lds16(ga0 + kk, la0);
    gl_lds16(ga1 + kk, la1);
    gl_lds16(gb0 + kk, lb0);
    gl_lds16(gb1 + kk, lb1);
    __syncthreads();
    bf16x8 af[4], bg[4];
#pragma unroll
    for (int mi = 0; mi < 4; ++mi)
      af[mi] = *(const bf16x8*)(As + (wm + mi * 16 + fr) * 32 + q * 8);
#pragma unroll
    for (int ni = 0; ni < 4; ++ni)
      bg[ni] = *(const bf16x8*)(Bs + (wn + ni * 16 + fr) * 32 + q * 8);
#pragma unroll
    for (int mi = 0; mi < 4; ++mi)
#pragma unroll
      for (int ni = 0; ni < 4; ++ni)
        acc[mi][ni] = mfma16(af[mi], bg[ni], acc[mi][ni]);
    __syncthreads();
  }

  size_t coff = (size_t)z * (size_t)cz;
#pragma unroll
  for (int mi = 0; mi < 4; ++mi)
#pragma unroll
    for (int ni = 0; ni < 4; ++ni) {
      int row = m0g + wm + mi * 16 + q * 4;
      int col = n0g + wn + ni * 16 + fr;
#pragma unroll
      for (int r = 0; r < 4; ++r) {
        float v = acc[mi][ni][r];
        if constexpr (OBF) {
          ((short*)C0)[coff + (size_t)(row + r) * LDIM + col] = (short)f2bf(v);
        } else {
          ((float*)C0)[coff + (size_t)(row + r) * LDIM + col] = v;
        }
      }
    }
}

// ---------------------------------------------------------------------------
// energy_f GEMM: both operands M-contiguous (k-strided) bf16; padded LDS,
// register transpose staging. C fp32.
// ---------------------------------------------------------------------------
__global__ __launch_bounds__(256, 2) void gemm_t(
    const short* __restrict__ A0, long az,
    const short* __restrict__ B0, long bz,
    float* __restrict__ C0, long cz) {
  __shared__ __align__(16) short As[128 * 40];
  __shared__ __align__(16) short Bs[128 * 40];
  int tid = threadIdx.x;
  int z = blockIdx.z;
  int m0g = blockIdx.y * 128, n0g = blockIdx.x * 128;
  const short* Abz = A0 + (size_t)z * (size_t)az;
  const short* Bbz = B0 + (size_t)z * (size_t)bz;
  int lane = tid & 63, wv = tid >> 6;
  int wm = (wv >> 1) * 64, wn = (wv & 1) * 64;
  int fr = lane & 15, q = lane >> 4;
  int mp = (tid & 63) * 2, k0 = (tid >> 6) * 8;

  f32x4 acc[4][4];
#pragma unroll
  for (int mi = 0; mi < 4; ++mi)
#pragma unroll
    for (int ni = 0; ni < 4; ++ni) acc[mi][ni] = (f32x4){0.f, 0.f, 0.f, 0.f};

  for (int kk = 0; kk < 512; kk += 32) {
    {
      const short* s = Abz + (size_t)(kk + k0) * 512 + m0g + mp;
      s16x8 c0, c1;
#pragma unroll
      for (int j = 0; j < 8; ++j) {
        unsigned v = *(const unsigned*)(s + (size_t)j * 512);
        c0[j] = (short)(v & 0xffffu);
        c1[j] = (short)(v >> 16);
      }
      *(s16x8*)(As + mp * 40 + k0) = c0;
      *(s16x8*)(As + (mp + 1) * 40 + k0) = c1;
    }
    {
      const short* s = Bbz + (size_t)(kk + k0) * 512 + n0g + mp;
      s16x8 c0, c1;
#pragma unroll
      for (int j = 0; j < 8; ++j) {
        unsigned v = *(const unsigned*)(s + (size_t)j * 512);
        c0[j] = (short)(v & 0xffffu);
        c1[j] = (short)(v >> 16);
      }
      *(s16x8*)(Bs + mp * 40 + k0) = c0;
      *(s16x8*)(Bs + (mp + 1) * 40 + k0) = c1;
    }
    __syncthreads();
    bf16x8 af[4], bg[4];
#pragma unroll
    for (int mi = 0; mi < 4; ++mi)
      af[mi] = *(const bf16x8*)(As + (wm + mi * 16 + fr) * 40 + q * 8);
#pragma unroll
    for (int ni = 0; ni < 4; ++ni)
      bg[ni] = *(const bf16x8*)(Bs + (wn + ni * 16 + fr) * 40 + q * 8);
#pragma unroll
    for (int mi = 0; mi < 4; ++mi)
#pragma unroll
      for (int ni = 0; ni < 4; ++ni)
        acc[mi][ni] = mfma16(af[mi], bg[ni], acc[mi][ni]);
    __syncthreads();
  }

  size_t coff = (size_t)z * (size_t)cz;
#pragma unroll
  for (int mi = 0; mi < 4; ++mi)
#pragma unroll
    for (int ni = 0; ni < 4; ++ni) {
      int row = m0g + wm + mi * 16 + q * 4;
      int col = n0g + wn + ni * 16 + fr;
#pragma unroll
      for (int r = 0; r < 4; ++r)
        C0[coff + (size_t)(row + r) * LDIM + col] = acc[mi][ni][r];
    }
}

// ---------------------------------------------------------------------------
// Row softmax over 512 logits with 8-way split-K partial sum; output scaled
// by gamma (folds the branch gamma into the attention weights; exact for
// power-of-two gamma, negligible otherwise vs bf16 rounding).
// ---------------------------------------------------------------------------
__global__ __launch_bounds__(256, 4) void softmax8_k(const float* __restrict__ Ep,
                                                     const float* __restrict__ gp,
                                                     short* __restrict__ A) {
  int tid = threadIdx.x;
  int lane = tid & 63, wv = tid >> 6;
  int row = blockIdx.x * 4 + wv;        // n*512 + r
  int n = row >> 9, h = row & 511;
  const float* base = Ep + (size_t)(n * 8) * HW + (size_t)h * 512 + lane * 8;
  float v[8] = {0.f, 0.f, 0.f, 0.f, 0.f, 0.f, 0.f, 0.f};
#pragma unroll
  for (int cc = 0; cc < 8; ++cc) {
    const float* e = base + (size_t)cc * HW;
    float4 a = *(const float4*)e;
    float4 b = *(const float4*)(e + 4);
    v[0] += a.x; v[1] += a.y; v[2] += a.z; v[3] += a.w;
    v[4] += b.x; v[5] += b.y; v[6] += b.z; v[7] += b.w;
  }
  float m = v[0];
#pragma unroll
  for (int j = 1; j < 8; ++j) m = fmaxf(m, v[j]);
#pragma unroll
  for (int off = 32; off >= 1; off >>= 1) m = fmaxf(m, __shfl_xor(m, off));
  float s = 0.f;
#pragma unroll
  for (int j = 0; j < 8; ++j) {
    v[j] = __expf(v[j] - m);
    s += v[j];
  }
#pragma unroll
  for (int off = 32; off >= 1; off >>= 1) s += __shfl_xor(s, off);
  float sc = gp[0] / s;
  s16x8 o;
#pragma unroll
  for (int j = 0; j < 8; ++j) o[j] = (short)f2bf(v[j] * sc);
  *(s16x8*)(A + (size_t)row * LDIM + lane * 8) = o;
}

// ---------------------------------------------------------------------------
// Fused dual-branch attention GEMM + final combine:
//   acc  = sum_g At[h][g]*VtT[o][w][g]   (branch T; At pre-scaled by gamma_t)
//        + sum_v Vf[o][h][v]*Af[w][v]    (branch F; Af pre-scaled by gamma_f)
//   out[o][h][w] = 3*x[o][h][w] + acc + (gt*tvb[o] + gf*fvb[o])
// All four operands K-contiguous bf16; 32 MFMA per 8 global_load_lds per
// K-step (2x MFMA:staging ratio of gemm_a). Writes final fp32 directly;
// eliminates ZT/ZF materialization and the old final_k gather pass.
// ---------------------------------------------------------------------------
__global__ __launch_bounds__(256, 3) void gemm_tf(
    const short* __restrict__ At, const short* __restrict__ Vt,
    const short* __restrict__ Vf, const short* __restrict__ Af,
    const short* __restrict__ xb,
    const float* __restrict__ tvb, const float* __restrict__ fvb,
    const float* __restrict__ tg, const float* __restrict__ fg,
    float* __restrict__ out) {
  __shared__ __align__(16) short As1[128 * 32];
  __shared__ __align__(16) short Bs1[128 * 32];
  __shared__ __align__(16) short As2[128 * 32];
  __shared__ __align__(16) short Bs2[128 * 32];
  int tid = threadIdx.x;
  int z = blockIdx.z;             // n*64 + o
  int n = z >> 6, o = z & 63;
  int m0g = blockIdx.y * 128, n0g = blockIdx.x * 128;
  const short* A1 = At + (size_t)n * HW;      // [h][g], gamma_t folded
  const short* B1 = Vt + (size_t)z * HW;      // VtT [o][w][g]
  const short* A2 = Vf + (size_t)z * HW;      // Vf  [o][h][v]
  const short* B2 = Af + (size_t)n * HW;      // [w][v], gamma_f folded
  int lane = tid & 63, wv = tid >> 6;
  int wm = (wv >> 1) * 64, wn = (wv & 1) * 64;
  int fr = lane & 15, q = lane >> 4;

  int srow = lane >> 2;
  int sch = (lane & 3) * 8;
  const short* g1a = A1 + (size_t)(m0g + wv * 32 + srow) * 512 + sch;
  const short* g1b = B1 + (size_t)(n0g + wv * 32 + srow) * 512 + sch;
  const short* g2a = A2 + (size_t)(m0g + wv * 32 + srow) * 512 + sch;
  const short* g2b = B2 + (size_t)(n0g + wv * 32 + srow) * 512 + sch;
  short* l1a = As1 + (wv * 32) * 32;
  short* l1b = Bs1 + (wv * 32) * 32;
  short* l2a = As2 + (wv * 32) * 32;
  short* l2b = Bs2 + (wv * 32) * 32;

  f32x4 acc[4][4];
#pragma unroll
  for (int mi = 0; mi < 4; ++mi)
#pragma unroll
    for (int ni = 0; ni < 4; ++ni) acc[mi][ni] = (f32x4){0.f, 0.f, 0.f, 0.f};

  for (int kk = 0; kk < 512; kk += 32) {
    gl_lds16(g1a + kk, l1a);
    gl_lds16(g1a + kk + 16 * 512, l1a + 16 * 32);
    gl_lds16(g1b + kk, l1b);
    gl_lds16(g1b + kk + 16 * 512, l1b + 16 * 32);
    gl_lds16(g2a + kk, l2a);
    gl_lds16(g2a + kk + 16 * 512, l2a + 16 * 32);
    gl_lds16(g2b + kk, l2b);
    gl_lds16(g2b + kk + 16 * 512, l2b + 16 * 32);
    __syncthreads();
    {
      bf16x8 a1[4], b1[4];
#pragma unroll
      for (int mi = 0; mi < 4; ++mi)
        a1[mi] = *(const bf16x8*)(As1 + (wm + mi * 16 + fr) * 32 + q * 8);
#pragma unroll
      for (int ni = 0; ni < 4; ++ni)
        b1[ni] = *(const bf16x8*)(Bs1 + (wn + ni * 16 + fr) * 32 + q * 8);
#pragma unroll
      for (int mi = 0; mi < 4; ++mi)
#pragma unroll
        for (int ni = 0; ni < 4; ++ni)
          acc[mi][ni] = mfma16(a1[mi], b1[ni], acc[mi][ni]);
    }
    {
      bf16x8 a2[4], b2[4];
#pragma unroll
      for (int mi = 0; mi < 4; ++mi)
        a2[mi] = *(const bf16x8*)(As2 + (wm + mi * 16 + fr) * 32 + q * 8);
#pragma unroll
      for (int ni = 0; ni < 4; ++ni)
        b2[ni] = *(const bf16x8*)(Bs2 + (wn + ni * 16 + fr) * 32 + q * 8);
#pragma unroll
      for (int mi = 0; mi < 4; ++mi)
#pragma unroll
        for (int ni = 0; ni < 4; ++ni)
          acc[mi][ni] = mfma16(a2[mi], b2[ni], acc[mi][ni]);
    }
    __syncthreads();
  }

  float cb = tg[0] * tvb[o] + fg[0] * fvb[o];
  size_t zoff = (size_t)z * HW;
#pragma unroll
  for (int mi = 0; mi < 4; ++mi)
#pragma unroll
    for (int ni = 0; ni < 4; ++ni) {
      int row = m0g + wm + mi * 16 + q * 4;
      int col = n0g + wn + ni * 16 + fr;
#pragma unroll
      for (int r = 0; r < 4; ++r) {
        size_t idx = zoff + (size_t)(row + r) * LDIM + col;
        out[idx] = 3.f * bf2f(xb[idx]) + acc[mi][ni][r] + cb;
      }
    }
}

// ---------------------------------------------------------------------------
extern "C" void kernel_launch(void* const* d_in, const int* in_sizes, int n_in,
                              void* d_out, int out_size, void* d_ws, size_t ws_size,
                              hipStream_t stream) {
  (void)in_sizes; (void)n_in; (void)out_size;
  const float* x   = (const float*)d_in[0];
  const float* tqw = (const float*)d_in[1];
  const float* tqb = (const float*)d_in[2];
  const float* tkw = (const float*)d_in[3];
  const float* tkb = (const float*)d_in[4];
  const float* tvw = (const float*)d_in[5];
  const float* tvb = (const float*)d_in[6];
  const float* tg  = (const float*)d_in[7];
  const float* fqw = (const float*)d_in[8];
  const float* fqb = (const float*)d_in[9];
  const float* fkw = (const float*)d_in[10];
  const float* fkb = (const float*)d_in[11];
  const float* fvw = (const float*)d_in[12];
  const float* fvb = (const float*)d_in[13];
  const float* fg  = (const float*)d_in[14];
  float* out = (float*)d_out;

  // per-batch: xb 32M + xt/VtT 32M + Vf 32M + QK 16M = 112 MiB
  const size_t per_n = ((size_t)64 * HW * 2) * 3     // xb, xt(VtT), Vf
                     + ((size_t)8 * HW * 2) * 4;     // QT,KT,QF,KF
  int nb = (ws_size >= 4 * per_n) ? 4
         : (ws_size >= 2 * per_n) ? 2 : 1;

  char* wb = (char*)d_ws;
  size_t sz_x  = (size_t)nb * 64 * HW * 2;
  size_t sz_qk = (size_t)nb * 8 * HW * 2;
  short* xb = (short*)(wb);
  short* xt = (short*)(wb + sz_x);           // becomes VtT in place after conv_v
  short* Vf = (short*)(wb + 2 * sz_x);
  short* QT = (short*)(wb + 3 * sz_x);
  short* KT = (short*)(wb + 3 * sz_x + sz_qk);
  short* QF = (short*)(wb + 3 * sz_x + 2 * sz_qk);
  short* KF = (short*)(wb + 3 * sz_x + 3 * sz_qk);
  short* At = QT;   // alias: QT dead once energy_t gemm has run
  short* Af = QF;   // alias: QF dead once energy_f gemm has run

  for (int n0 = 0; n0 < 4; n0 += nb) {
    const float* xn = x + (size_t)n0 * 64 * HW;
    float* outn = out + (size_t)n0 * 64 * HW;
    // energy partials live in the (not-yet-written) output buffer:
    // EbT/EbF each nb*8 MiB, dead before gemm_tf writes outn.
    float* EbT = outn;
    float* EbF = outn + (size_t)nb * 8 * HW;

    cast_k<<<dim3(8, 8, nb * 64), dim3(256), 0, stream>>>(xn, xb, xt);
    conv_qkvf_k<<<dim3(nb * 2048), dim3(256), 0, stream>>>(
        xb, tqw, tqb, tkw, tkb, fqw, fqb, fkw, fkb, fvw, QT, KT, QF, KF, Vf);
    conv_v_k<<<dim3(nb * 2048), dim3(256), 0, stream>>>(xt, tvw, xt);
    // energy_t partials: per z=(n*8+c), Qt[z] @ Kt[z]^T (K=512)
    gemm_a<false><<<dim3(4, 4, nb * 8), dim3(256), 0, stream>>>(
        QT, (long)HW, 0, KT, (long)HW, 0, EbT, (long)HW);
    softmax8_k<<<dim3(nb * 128), dim3(256), 0, stream>>>(EbT, tg, At);
    // energy_f partials: per z, E[w][v] = sum_h Qf[z][h][w]*Kf[z][h][v]
    gemm_t<<<dim3(4, 4, nb * 8), dim3(256), 0, stream>>>(
        QF, (long)HW, KF, (long)HW, EbF, (long)HW);
    softmax8_k<<<dim3(nb * 128), dim3(256), 0, stream>>>(EbF, fg, Af);
    // fused dual-branch attention + residual + bias -> final output
    gemm_tf<<<dim3(4, 4, nb * 64), dim3(256), 0, stream>>>(
        At, xt, Vf, Af, xb, tvb, fvb, tg, fg, outn);
  }
}

// Round 2
// 952.483 us; speedup vs baseline: 1.0259x; 1.0020x over previous
//
#include <hip/hip_runtime.h>
#include <stdint.h>

#define HW 262144      // 512*512
#define LDIM 512

typedef __bf16 bf16x8 __attribute__((ext_vector_type(8)));
typedef float f32x4 __attribute__((ext_vector_type(4)));
typedef short s16x8 __attribute__((ext_vector_type(8)));
typedef short s16x4 __attribute__((ext_vector_type(4)));

__device__ __forceinline__ unsigned short f2bf(float f) {
  union { float f; unsigned u; } v; v.f = f;
  unsigned r = v.u + 0x7fffu + ((v.u >> 16) & 1u);
  return (unsigned short)(r >> 16);
}

__device__ __forceinline__ float bf2f(short s) {
  union { unsigned u; float f; } v;
  v.u = ((unsigned)(unsigned short)s) << 16;
  return v.f;
}

__device__ __forceinline__ s16x8 pack_bf8(float4 a, float4 b) {
  s16x8 r;
  r[0] = (short)f2bf(a.x); r[1] = (short)f2bf(a.y);
  r[2] = (short)f2bf(a.z); r[3] = (short)f2bf(a.w);
  r[4] = (short)f2bf(b.x); r[5] = (short)f2bf(b.y);
  r[6] = (short)f2bf(b.z); r[7] = (short)f2bf(b.w);
  return r;
}

__device__ __forceinline__ f32x4 mfma16(bf16x8 a, bf16x8 b, f32x4 c) {
  return __builtin_amdgcn_mfma_f32_16x16x32_bf16(a, b, c, 0, 0, 0);
}

// async global->LDS, 16B per lane, LDS dest = wave-uniform base + lane*16
__device__ __forceinline__ void gl_lds16(const short* g, short* l) {
  __builtin_amdgcn_global_load_lds(
      (const __attribute__((address_space(1))) void*)g,
      (__attribute__((address_space(3))) void*)l, 16, 0, 0);
}

// ---------------------------------------------------------------------------
// Fused Q/K/V conv straight from fp32 x: 128 positions x 160 out channels.
// co 0..7=Qt, 8..15=Kt, 16..23=Qf, 24..31=Kf (biased, bf16 out);
// co 32..95=Vt (tvw, no bias), co 96..159=Vf (fvw, no bias; fv/tv biases are
// folded into the gemm_tf epilogue constant). The expensive channel-gather of
// x is paid exactly once for all 160 outputs.
// ---------------------------------------------------------------------------
__global__ __launch_bounds__(256, 2) void conv_all_k(
    const float* __restrict__ x,
    const float* __restrict__ tqw, const float* __restrict__ tqb,
    const float* __restrict__ tkw, const float* __restrict__ tkb,
    const float* __restrict__ fqw, const float* __restrict__ fqb,
    const float* __restrict__ fkw, const float* __restrict__ fkb,
    const float* __restrict__ tvw, const float* __restrict__ fvw,
    short* __restrict__ QT, short* __restrict__ KT,
    short* __restrict__ QF, short* __restrict__ KF,
    short* __restrict__ Vt, short* __restrict__ Vf) {
  __shared__ __align__(16) short As[128 * 72];   // x^T tile [p][ci] (bf16)
  __shared__ __align__(16) short Ws[160 * 72];   // weights [co][ci]
  __shared__ float bia[32];
  int tid = threadIdx.x;
  int n = blockIdx.x >> 11;
  int p0 = (blockIdx.x & 2047) << 7;
#pragma unroll
  for (int i = 0; i < 5; ++i) {
    int idx = i * 256 + tid;                 // 0..1279 -> 160 rows x 8 chunks
    int co = idx >> 3, k0 = (idx & 7) * 8;
    const float* wrow = (co < 8)  ? tqw + co * 64
                      : (co < 16) ? tkw + (co - 8) * 64
                      : (co < 24) ? fqw + (co - 16) * 64
                      : (co < 32) ? fkw + (co - 24) * 64
                      : (co < 96) ? tvw + (co - 32) * 64
                                  : fvw + (co - 96) * 64;
    float4 f0 = *(const float4*)(wrow + k0);
    float4 f1 = *(const float4*)(wrow + k0 + 4);
    *(s16x8*)(Ws + co * 72 + k0) = pack_bf8(f0, f1);
  }
  if (tid < 32) {
    const float* bsrc = (tid < 8) ? tqb : (tid < 16) ? tkb : (tid < 24) ? fqb : fkb;
    bia[tid] = bsrc[tid & 7];
  }
  {
    // 4 positions x 8 channels per thread; 16B fp32 loads, bf16 in-reg.
    int mp = (tid & 31) * 4, k0 = (tid >> 5) * 8;
    const float* sp = x + ((size_t)(n * 64 + k0)) * HW + p0 + mp;
    s16x8 t0, t1, t2, t3;
#pragma unroll
    for (int j = 0; j < 8; ++j) {
      float4 v = *(const float4*)(sp + (size_t)j * HW);
      t0[j] = (short)f2bf(v.x); t1[j] = (short)f2bf(v.y);
      t2[j] = (short)f2bf(v.z); t3[j] = (short)f2bf(v.w);
    }
    *(s16x8*)(As + (mp + 0) * 72 + k0) = t0;
    *(s16x8*)(As + (mp + 1) * 72 + k0) = t1;
    *(s16x8*)(As + (mp + 2) * 72 + k0) = t2;
    *(s16x8*)(As + (mp + 3) * 72 + k0) = t3;
  }
  __syncthreads();
  int lane = tid & 63, wv = tid >> 6, fr = lane & 15, q = lane >> 4;
  int wm = wv * 32;
  f32x4 acc[2][10];
#pragma unroll
  for (int mi = 0; mi < 2; ++mi)
#pragma unroll
    for (int ni = 0; ni < 10; ++ni) acc[mi][ni] = (f32x4){0.f, 0.f, 0.f, 0.f};
#pragma unroll
  for (int ks = 0; ks < 2; ++ks) {
    bf16x8 af[2];
#pragma unroll
    for (int mi = 0; mi < 2; ++mi)
      af[mi] = *(const bf16x8*)(As + (wm + mi * 16 + fr) * 72 + ks * 32 + q * 8);
#pragma unroll
    for (int ni = 0; ni < 10; ++ni) {
      bf16x8 bw = *(const bf16x8*)(Ws + (ni * 16 + fr) * 72 + ks * 32 + q * 8);
      acc[0][ni] = mfma16(af[0], bw, acc[0][ni]);
      acc[1][ni] = mfma16(af[1], bw, acc[1][ni]);
    }
  }
#pragma unroll
  for (int mi = 0; mi < 2; ++mi)
#pragma unroll
    for (int ni = 0; ni < 10; ++ni) {
      int pl = wm + mi * 16 + q * 4;
      int co = ni * 16 + fr;
      float b = (co < 32) ? bia[co] : 0.f;
      short* dst;
      if (co < 32) {
        short* dd = (co < 8) ? QT : (co < 16) ? KT : (co < 24) ? QF : KF;
        dst = dd + ((size_t)(n * 8 + (co & 7))) * HW;
      } else if (co < 96) {
        dst = Vt + ((size_t)(n * 64 + (co - 32))) * HW;
      } else {
        dst = Vf + ((size_t)(n * 64 + (co - 96))) * HW;
      }
      s16x4 sv;
#pragma unroll
      for (int r = 0; r < 4; ++r) sv[r] = (short)f2bf(acc[mi][ni][r] + b);
      *(s16x4*)(dst + p0 + pl) = sv;
    }
}

// ---------------------------------------------------------------------------
// In-place 512x512 bf16 transpose of one plane, via 64x64 tile pairs.
// blockIdx.x in [0,36): upper-triangle pair (ti,tj), ti<=tj; blockIdx.y=plane.
// Each pair touched by exactly one block: reads both tiles to LDS (transposed
// scatter), barrier, writes swapped -> race-free in-place.
// ---------------------------------------------------------------------------
__global__ __launch_bounds__(256, 4) void trans_k(short* __restrict__ V) {
  __shared__ short La[64][72];
  __shared__ short Lb[64][72];
  short* p = V + (size_t)blockIdx.y * HW;
  int b = blockIdx.x;
  int ti = 0;
  while (b >= 8 - ti) { b -= 8 - ti; ++ti; }
  int tj = ti + b;
  int tid = threadIdx.x;
  int hl = tid >> 4, wl = (tid & 15) * 4;
#pragma unroll
  for (int it = 0; it < 4; ++it) {
    int r = hl + it * 16;
    s16x4 va = *(const s16x4*)(p + (size_t)(ti * 64 + r) * 512 + tj * 64 + wl);
    La[wl + 0][r] = va[0]; La[wl + 1][r] = va[1];
    La[wl + 2][r] = va[2]; La[wl + 3][r] = va[3];
    if (ti != tj) {
      s16x4 vb = *(const s16x4*)(p + (size_t)(tj * 64 + r) * 512 + ti * 64 + wl);
      Lb[wl + 0][r] = vb[0]; Lb[wl + 1][r] = vb[1];
      Lb[wl + 2][r] = vb[2]; Lb[wl + 3][r] = vb[3];
    }
  }
  __syncthreads();
#pragma unroll
  for (int it = 0; it < 4; ++it) {
    int c = hl + it * 16;
    *(s16x4*)(p + (size_t)(tj * 64 + c) * 512 + ti * 64 + wl) =
        *(const s16x4*)(&La[c][wl]);
    if (ti != tj)
      *(s16x4*)(p + (size_t)(ti * 64 + c) * 512 + tj * 64 + wl) =
          *(const s16x4*)(&Lb[c][wl]);
  }
}

// ---------------------------------------------------------------------------
// Async GEMM (m97 structure): C[m][n] = sum_k A[m][k]*B[n][k], K=512, ld=512,
// both operands K-contiguous bf16. 128x128 tile, BK=32, unpadded [128][32]
// LDS, staged via global_load_lds dwordx4. (energy_t partials, fp32 out)
// ---------------------------------------------------------------------------
template<bool OBF>
__global__ __launch_bounds__(256, 4) void gemm_a(
    const short* __restrict__ A0, long az, int zshA,
    const short* __restrict__ B0, long bz, int zshB,
    void* __restrict__ C0, long cz) {
  __shared__ __align__(16) short As[128 * 32];
  __shared__ __align__(16) short Bs[128 * 32];
  int tid = threadIdx.x;
  int z = blockIdx.z;
  int m0g = blockIdx.y * 128, n0g = blockIdx.x * 128;
  const short* Abz = A0 + (size_t)(z >> zshA) * (size_t)az;
  const short* Bbz = B0 + (size_t)(z >> zshB) * (size_t)bz;
  int lane = tid & 63, wv = tid >> 6;
  int wm = (wv >> 1) * 64, wn = (wv & 1) * 64;
  int fr = lane & 15, q = lane >> 4;

  int srow = lane >> 2;         // 0..15
  int sch = (lane & 3) * 8;     // short offset within row
  const short* ga0 = Abz + (size_t)(m0g + wv * 32 + srow) * 512 + sch;
  const short* ga1 = ga0 + 16 * 512;
  const short* gb0 = Bbz + (size_t)(n0g + wv * 32 + srow) * 512 + sch;
  const short* gb1 = gb0 + 16 * 512;
  short* la0 = As + (wv * 32) * 32;
  short* la1 = As + (wv * 32 + 16) * 32;
  short* lb0 = Bs + (wv * 32) * 32;
  short* lb1 = Bs + (wv * 32 + 16) * 32;

  f32x4 acc[4][4];
#pragma unroll
  for (int mi = 0; mi < 4; ++mi)
#pragma unroll
    for (int ni = 0; ni < 4; ++ni) acc[mi][ni] = (f32x4){0.f, 0.f, 0.f, 0.f};

  for (int kk = 0; kk < 512; kk += 32) {
    gl_lds16(ga0 + kk, la0);
    gl_lds16(ga1 + kk, la1);
    gl_lds16(gb0 + kk, lb0);
    gl_lds16(gb1 + kk, lb1);
    __syncthreads();
    bf16x8 af[4], bg[4];
#pragma unroll
    for (int mi = 0; mi < 4; ++mi)
      af[mi] = *(const bf16x8*)(As + (wm + mi * 16 + fr) * 32 + q * 8);
#pragma unroll
    for (int ni = 0; ni < 4; ++ni)
      bg[ni] = *(const bf16x8*)(Bs + (wn + ni * 16 + fr) * 32 + q * 8);
#pragma unroll
    for (int mi = 0; mi < 4; ++mi)
#pragma unroll
      for (int ni = 0; ni < 4; ++ni)
        acc[mi][ni] = mfma16(af[mi], bg[ni], acc[mi][ni]);
    __syncthreads();
  }

  size_t coff = (size_t)z * (size_t)cz;
#pragma unroll
  for (int mi = 0; mi < 4; ++mi)
#pragma unroll
    for (int ni = 0; ni < 4; ++ni) {
      int row = m0g + wm + mi * 16 + q * 4;
      int col = n0g + wn + ni * 16 + fr;
#pragma unroll
      for (int r = 0; r < 4; ++r) {
        float v = acc[mi][ni][r];
        if constexpr (OBF) {
          ((short*)C0)[coff + (size_t)(row + r) * LDIM + col] = (short)f2bf(v);
        } else {
          ((float*)C0)[coff + (size_t)(row + r) * LDIM + col] = v;
        }
      }
    }
}

// ---------------------------------------------------------------------------
// energy_f GEMM: both operands M-contiguous (k-strided) bf16; padded LDS,
// register transpose staging. C fp32.
// ---------------------------------------------------------------------------
__global__ __launch_bounds__(256, 2) void gemm_t(
    const short* __restrict__ A0, long az,
    const short* __restrict__ B0, long bz,
    float* __restrict__ C0, long cz) {
  __shared__ __align__(16) short As[128 * 40];
  __shared__ __align__(16) short Bs[128 * 40];
  int tid = threadIdx.x;
  int z = blockIdx.z;
  int m0g = blockIdx.y * 128, n0g = blockIdx.x * 128;
  const short* Abz = A0 + (size_t)z * (size_t)az;
  const short* Bbz = B0 + (size_t)z * (size_t)bz;
  int lane = tid & 63, wv = tid >> 6;
  int wm = (wv >> 1) * 64, wn = (wv & 1) * 64;
  int fr = lane & 15, q = lane >> 4;
  int mp = (tid & 63) * 2, k0 = (tid >> 6) * 8;

  f32x4 acc[4][4];
#pragma unroll
  for (int mi = 0; mi < 4; ++mi)
#pragma unroll
    for (int ni = 0; ni < 4; ++ni) acc[mi][ni] = (f32x4){0.f, 0.f, 0.f, 0.f};

  for (int kk = 0; kk < 512; kk += 32) {
    {
      const short* s = Abz + (size_t)(kk + k0) * 512 + m0g + mp;
      s16x8 c0, c1;
#pragma unroll
      for (int j = 0; j < 8; ++j) {
        unsigned v = *(const unsigned*)(s + (size_t)j * 512);
        c0[j] = (short)(v & 0xffffu);
        c1[j] = (short)(v >> 16);
      }
      *(s16x8*)(As + mp * 40 + k0) = c0;
      *(s16x8*)(As + (mp + 1) * 40 + k0) = c1;
    }
    {
      const short* s = Bbz + (size_t)(kk + k0) * 512 + n0g + mp;
      s16x8 c0, c1;
#pragma unroll
      for (int j = 0; j < 8; ++j) {
        unsigned v = *(const unsigned*)(s + (size_t)j * 512);
        c0[j] = (short)(v & 0xffffu);
        c1[j] = (short)(v >> 16);
      }
      *(s16x8*)(Bs + mp * 40 + k0) = c0;
      *(s16x8*)(Bs + (mp + 1) * 40 + k0) = c1;
    }
    __syncthreads();
    bf16x8 af[4], bg[4];
#pragma unroll
    for (int mi = 0; mi < 4; ++mi)
      af[mi] = *(const bf16x8*)(As + (wm + mi * 16 + fr) * 40 + q * 8);
#pragma unroll
    for (int ni = 0; ni < 4; ++ni)
      bg[ni] = *(const bf16x8*)(Bs + (wn + ni * 16 + fr) * 40 + q * 8);
#pragma unroll
    for (int mi = 0; mi < 4; ++mi)
#pragma unroll
      for (int ni = 0; ni < 4; ++ni)
        acc[mi][ni] = mfma16(af[mi], bg[ni], acc[mi][ni]);
    __syncthreads();
  }

  size_t coff = (size_t)z * (size_t)cz;
#pragma unroll
  for (int mi = 0; mi < 4; ++mi)
#pragma unroll
    for (int ni = 0; ni < 4; ++ni) {
      int row = m0g + wm + mi * 16 + q * 4;
      int col = n0g + wn + ni * 16 + fr;
#pragma unroll
      for (int r = 0; r < 4; ++r)
        C0[coff + (size_t)(row + r) * LDIM + col] = acc[mi][ni][r];
    }
}

// ---------------------------------------------------------------------------
// Row softmax over 512 logits with 8-way split-K partial sum; output scaled
// by gamma (folds the branch gamma into the attention weights).
// ---------------------------------------------------------------------------
__global__ __launch_bounds__(256, 4) void softmax8_k(const float* __restrict__ Ep,
                                                     const float* __restrict__ gp,
                                                     short* __restrict__ A) {
  int tid = threadIdx.x;
  int lane = tid & 63, wv = tid >> 6;
  int row = blockIdx.x * 4 + wv;        // n*512 + r
  int n = row >> 9, h = row & 511;
  const float* base = Ep + (size_t)(n * 8) * HW + (size_t)h * 512 + lane * 8;
  float v[8] = {0.f, 0.f, 0.f, 0.f, 0.f, 0.f, 0.f, 0.f};
#pragma unroll
  for (int cc = 0; cc < 8; ++cc) {
    const float* e = base + (size_t)cc * HW;
    float4 a = *(const float4*)e;
    float4 b = *(const float4*)(e + 4);
    v[0] += a.x; v[1] += a.y; v[2] += a.z; v[3] += a.w;
    v[4] += b.x; v[5] += b.y; v[6] += b.z; v[7] += b.w;
  }
  float m = v[0];
#pragma unroll
  for (int j = 1; j < 8; ++j) m = fmaxf(m, v[j]);
#pragma unroll
  for (int off = 32; off >= 1; off >>= 1) m = fmaxf(m, __shfl_xor(m, off));
  float s = 0.f;
#pragma unroll
  for (int j = 0; j < 8; ++j) {
    v[j] = __expf(v[j] - m);
    s += v[j];
  }
#pragma unroll
  for (int off = 32; off >= 1; off >>= 1) s += __shfl_xor(s, off);
  float sc = gp[0] / s;
  s16x8 o;
#pragma unroll
  for (int j = 0; j < 8; ++j) o[j] = (short)f2bf(v[j] * sc);
  *(s16x8*)(A + (size_t)row * LDIM + lane * 8) = o;
}

// ---------------------------------------------------------------------------
// Fused dual-branch attention GEMM as ONE K=1024 GEMM (m97 structure):
//   K<512 :  A = At[n] (rows h, K-contig), B = VtT[z] (rows w, K-contig)
//   K>=512:  A = Vf[z] (rows h, K-contig), B = Af[n] (rows w, K-contig)
//   out[z][h][w] = 3*x[z][h][w] + acc + (gt*tvb[o] + gf*fvb[o])
// 16 KB LDS, 4 gl_lds + 16 MFMA per K-step. 1D grid with bijective XCD-aware
// decode: the 4 row-tiles (yt) sharing a B-panel (same nt,z) land on one XCD
// consecutively -> B-panel fetched once per XCD L2.
// ---------------------------------------------------------------------------
__global__ __launch_bounds__(256, 4) void gemm_tf(
    const short* __restrict__ At, const short* __restrict__ VtT,
    const short* __restrict__ Vf, const short* __restrict__ Af,
    const float* __restrict__ x,
    const float* __restrict__ tvb, const float* __restrict__ fvb,
    const float* __restrict__ tg, const float* __restrict__ fg,
    float* __restrict__ out, int Z) {
  __shared__ __align__(16) short As[128 * 32];
  __shared__ __align__(16) short Bs[128 * 32];
  int tid = threadIdx.x;
  // bijective decode of f -> (yt, nt, z); Z is even
  int f = blockIdx.x;
  int xcd = f & 7, j = f >> 3;
  int yt = j & 3;
  int pid = xcd * (Z >> 1) + (j >> 2);
  int nt = pid & 3, z = pid >> 2;
  int n = z >> 6, o = z & 63;
  int m0g = yt * 128, n0g = nt * 128;

  int lane = tid & 63, wv = tid >> 6;
  int wm = (wv >> 1) * 64, wn = (wv & 1) * 64;
  int fr = lane & 15, q = lane >> 4;
  int srow = lane >> 2;
  int sch = (lane & 3) * 8;
  short* la0 = As + (wv * 32) * 32;
  short* la1 = la0 + 16 * 32;
  short* lb0 = Bs + (wv * 32) * 32;
  short* lb1 = lb0 + 16 * 32;

  f32x4 acc[4][4];
#pragma unroll
  for (int mi = 0; mi < 4; ++mi)
#pragma unroll
    for (int ni = 0; ni < 4; ++ni) acc[mi][ni] = (f32x4){0.f, 0.f, 0.f, 0.f};

  const short* g1a = At + (size_t)n * HW + (size_t)(m0g + wv * 32 + srow) * 512 + sch;
  const short* g1b = VtT + (size_t)z * HW + (size_t)(n0g + wv * 32 + srow) * 512 + sch;
  for (int kk = 0; kk < 512; kk += 32) {
    gl_lds16(g1a + kk, la0);
    gl_lds16(g1a + kk + 16 * 512, la1);
    gl_lds16(g1b + kk, lb0);
    gl_lds16(g1b + kk + 16 * 512, lb1);
    __syncthreads();
    bf16x8 af[4], bg[4];
#pragma unroll
    for (int mi = 0; mi < 4; ++mi)
      af[mi] = *(const bf16x8*)(As + (wm + mi * 16 + fr) * 32 + q * 8);
#pragma unroll
    for (int ni = 0; ni < 4; ++ni)
      bg[ni] = *(const bf16x8*)(Bs + (wn + ni * 16 + fr) * 32 + q * 8);
#pragma unroll
    for (int mi = 0; mi < 4; ++mi)
#pragma unroll
      for (int ni = 0; ni < 4; ++ni)
        acc[mi][ni] = mfma16(af[mi], bg[ni], acc[mi][ni]);
    __syncthreads();
  }
  const short* g2a = Vf + (size_t)z * HW + (size_t)(m0g + wv * 32 + srow) * 512 + sch;
  const short* g2b = Af + (size_t)n * HW + (size_t)(n0g + wv * 32 + srow) * 512 + sch;
  for (int kk = 0; kk < 512; kk += 32) {
    gl_lds16(g2a + kk, la0);
    gl_lds16(g2a + kk + 16 * 512, la1);
    gl_lds16(g2b + kk, lb0);
    gl_lds16(g2b + kk + 16 * 512, lb1);
    __syncthreads();
    bf16x8 af[4], bg[4];
#pragma unroll
    for (int mi = 0; mi < 4; ++mi)
      af[mi] = *(const bf16x8*)(As + (wm + mi * 16 + fr) * 32 + q * 8);
#pragma unroll
    for (int ni = 0; ni < 4; ++ni)
      bg[ni] = *(const bf16x8*)(Bs + (wn + ni * 16 + fr) * 32 + q * 8);
#pragma unroll
    for (int mi = 0; mi < 4; ++mi)
#pragma unroll
      for (int ni = 0; ni < 4; ++ni)
        acc[mi][ni] = mfma16(af[mi], bg[ni], acc[mi][ni]);
    __syncthreads();
  }

  float cb = tg[0] * tvb[o] + fg[0] * fvb[o];
  size_t zoff = (size_t)z * HW;
#pragma unroll
  for (int mi = 0; mi < 4; ++mi)
#pragma unroll
    for (int ni = 0; ni < 4; ++ni) {
      int row = m0g + wm + mi * 16 + q * 4;
      int col = n0g + wn + ni * 16 + fr;
#pragma unroll
      for (int r = 0; r < 4; ++r) {
        size_t idx = zoff + (size_t)(row + r) * LDIM + col;
        out[idx] = 3.f * x[idx] + acc[mi][ni][r] + cb;
      }
    }
}

// ---------------------------------------------------------------------------
extern "C" void kernel_launch(void* const* d_in, const int* in_sizes, int n_in,
                              void* d_out, int out_size, void* d_ws, size_t ws_size,
                              hipStream_t stream) {
  (void)in_sizes; (void)n_in; (void)out_size;
  const float* x   = (const float*)d_in[0];
  const float* tqw = (const float*)d_in[1];
  const float* tqb = (const float*)d_in[2];
  const float* tkw = (const float*)d_in[3];
  const float* tkb = (const float*)d_in[4];
  const float* tvw = (const float*)d_in[5];
  const float* tvb = (const float*)d_in[6];
  const float* tg  = (const float*)d_in[7];
  const float* fqw = (const float*)d_in[8];
  const float* fqb = (const float*)d_in[9];
  const float* fkw = (const float*)d_in[10];
  const float* fkb = (const float*)d_in[11];
  const float* fvw = (const float*)d_in[12];
  const float* fvb = (const float*)d_in[13];
  const float* fg  = (const float*)d_in[14];
  float* out = (float*)d_out;

  // per-batch: Vt 32M + Vf 32M + QK 16M = 80 MiB
  const size_t per_n = ((size_t)64 * HW * 2) * 2     // Vt, Vf
                     + ((size_t)8 * HW * 2) * 4;     // QT,KT,QF,KF
  int nb = (ws_size >= 4 * per_n) ? 4
         : (ws_size >= 2 * per_n) ? 2 : 1;

  char* wb = (char*)d_ws;
  size_t sz_v  = (size_t)nb * 64 * HW * 2;
  size_t sz_qk = (size_t)nb * 8 * HW * 2;
  short* Vt = (short*)(wb);                  // transposed in place -> VtT
  short* Vf = (short*)(wb + sz_v);
  short* QT = (short*)(wb + 2 * sz_v);
  short* KT = (short*)(wb + 2 * sz_v + sz_qk);
  short* QF = (short*)(wb + 2 * sz_v + 2 * sz_qk);
  short* KF = (short*)(wb + 2 * sz_v + 3 * sz_qk);
  short* At = QT;   // alias: QT dead once energy_t gemm has run
  short* Af = QF;   // alias: QF dead once energy_f gemm has run

  for (int n0 = 0; n0 < 4; n0 += nb) {
    const float* xn = x + (size_t)n0 * 64 * HW;
    float* outn = out + (size_t)n0 * 64 * HW;
    // energy partials live in the (not-yet-written) output buffer:
    // EbT/EbF each nb*8 MiB, dead before gemm_tf writes outn.
    float* EbT = outn;
    float* EbF = outn + (size_t)nb * 8 * HW;

    conv_all_k<<<dim3(nb * 2048), dim3(256), 0, stream>>>(
        xn, tqw, tqb, tkw, tkb, fqw, fqb, fkw, fkb, tvw, fvw,
        QT, KT, QF, KF, Vt, Vf);
    trans_k<<<dim3(36, nb * 64), dim3(256), 0, stream>>>(Vt);
    // energy_t partials: per z=(n*8+c), Qt[z] @ Kt[z]^T (K=512)
    gemm_a<false><<<dim3(4, 4, nb * 8), dim3(256), 0, stream>>>(
        QT, (long)HW, 0, KT, (long)HW, 0, EbT, (long)HW);
    softmax8_k<<<dim3(nb * 128), dim3(256), 0, stream>>>(EbT, tg, At);
    // energy_f partials: per z, E[w][v] = sum_h Qf[z][h][w]*Kf[z][h][v]
    gemm_t<<<dim3(4, 4, nb * 8), dim3(256), 0, stream>>>(
        QF, (long)HW, KF, (long)HW, EbF, (long)HW);
    softmax8_k<<<dim3(nb * 128), dim3(256), 0, stream>>>(EbF, fg, Af);
    // fused dual-branch attention + residual + bias -> final output
    gemm_tf<<<dim3(16 * nb * 64), dim3(256), 0, stream>>>(
        At, Vt, Vf, Af, xn, tvb, fvb, tg, fg, outn, nb * 64);
  }
}

// Round 4
// 867.953 us; speedup vs baseline: 1.1258x; 1.0974x over previous
//
#include <hip/hip_runtime.h>
#include <stdint.h>

#define HW 262144      // 512*512
#define LDIM 512

typedef __bf16 bf16x8 __attribute__((ext_vector_type(8)));
typedef float f32x4 __attribute__((ext_vector_type(4)));
typedef short s16x8 __attribute__((ext_vector_type(8)));
typedef short s16x4 __attribute__((ext_vector_type(4)));

__device__ __forceinline__ unsigned short f2bf(float f) {
  union { float f; unsigned u; } v; v.f = f;
  unsigned r = v.u + 0x7fffu + ((v.u >> 16) & 1u);
  return (unsigned short)(r >> 16);
}

__device__ __forceinline__ float bf2f(short s) {
  union { unsigned u; float f; } v;
  v.u = ((unsigned)(unsigned short)s) << 16;
  return v.f;
}

__device__ __forceinline__ s16x8 pack_bf8(float4 a, float4 b) {
  s16x8 r;
  r[0] = (short)f2bf(a.x); r[1] = (short)f2bf(a.y);
  r[2] = (short)f2bf(a.z); r[3] = (short)f2bf(a.w);
  r[4] = (short)f2bf(b.x); r[5] = (short)f2bf(b.y);
  r[6] = (short)f2bf(b.z); r[7] = (short)f2bf(b.w);
  return r;
}

__device__ __forceinline__ f32x4 mfma16(bf16x8 a, bf16x8 b, f32x4 c) {
  return __builtin_amdgcn_mfma_f32_16x16x32_bf16(a, b, c, 0, 0, 0);
}

// async global->LDS, 16B per lane, LDS dest = wave-uniform base + lane*16
__device__ __forceinline__ void gl_lds16(const short* g, short* l) {
  __builtin_amdgcn_global_load_lds(
      (const __attribute__((address_space(1))) void*)g,
      (__attribute__((address_space(3))) void*)l, 16, 0, 0);
}

// ---------------------------------------------------------------------------
// Fused Q/K/V conv straight from fp32 x: 128 positions x 160 out channels.
// co 0..7=Qt, 8..15=Kt, 16..23=Qf, 24..31=Kf (biased, bf16 out);
// co 32..95=Vt (tvw, no bias), co 96..159=Vf (fvw, no bias; fv/tv biases are
// folded into the gemm_tf epilogue constant).
// ---------------------------------------------------------------------------
__global__ __launch_bounds__(256, 2) void conv_all_k(
    const float* __restrict__ x,
    const float* __restrict__ tqw, const float* __restrict__ tqb,
    const float* __restrict__ tkw, const float* __restrict__ tkb,
    const float* __restrict__ fqw, const float* __restrict__ fqb,
    const float* __restrict__ fkw, const float* __restrict__ fkb,
    const float* __restrict__ tvw, const float* __restrict__ fvw,
    short* __restrict__ QT, short* __restrict__ KT,
    short* __restrict__ QF, short* __restrict__ KF,
    short* __restrict__ Vt, short* __restrict__ Vf) {
  __shared__ __align__(16) short As[128 * 72];   // x^T tile [p][ci] (bf16)
  __shared__ __align__(16) short Ws[160 * 72];   // weights [co][ci]
  __shared__ float bia[32];
  int tid = threadIdx.x;
  int n = blockIdx.x >> 11;
  int p0 = (blockIdx.x & 2047) << 7;
#pragma unroll
  for (int i = 0; i < 5; ++i) {
    int idx = i * 256 + tid;                 // 0..1279 -> 160 rows x 8 chunks
    int co = idx >> 3, k0 = (idx & 7) * 8;
    const float* wrow = (co < 8)  ? tqw + co * 64
                      : (co < 16) ? tkw + (co - 8) * 64
                      : (co < 24) ? fqw + (co - 16) * 64
                      : (co < 32) ? fkw + (co - 24) * 64
                      : (co < 96) ? tvw + (co - 32) * 64
                                  : fvw + (co - 96) * 64;
    float4 f0 = *(const float4*)(wrow + k0);
    float4 f1 = *(const float4*)(wrow + k0 + 4);
    *(s16x8*)(Ws + co * 72 + k0) = pack_bf8(f0, f1);
  }
  if (tid < 32) {
    const float* bsrc = (tid < 8) ? tqb : (tid < 16) ? tkb : (tid < 24) ? fqb : fkb;
    bia[tid] = bsrc[tid & 7];
  }
  {
    int mp = (tid & 31) * 4, k0 = (tid >> 5) * 8;
    const float* sp = x + ((size_t)(n * 64 + k0)) * HW + p0 + mp;
    s16x8 t0, t1, t2, t3;
#pragma unroll
    for (int j = 0; j < 8; ++j) {
      float4 v = *(const float4*)(sp + (size_t)j * HW);
      t0[j] = (short)f2bf(v.x); t1[j] = (short)f2bf(v.y);
      t2[j] = (short)f2bf(v.z); t3[j] = (short)f2bf(v.w);
    }
    *(s16x8*)(As + (mp + 0) * 72 + k0) = t0;
    *(s16x8*)(As + (mp + 1) * 72 + k0) = t1;
    *(s16x8*)(As + (mp + 2) * 72 + k0) = t2;
    *(s16x8*)(As + (mp + 3) * 72 + k0) = t3;
  }
  __syncthreads();
  int lane = tid & 63, wv = tid >> 6, fr = lane & 15, q = lane >> 4;
  int wm = wv * 32;
  f32x4 acc[2][10];
#pragma unroll
  for (int mi = 0; mi < 2; ++mi)
#pragma unroll
    for (int ni = 0; ni < 10; ++ni) acc[mi][ni] = (f32x4){0.f, 0.f, 0.f, 0.f};
#pragma unroll
  for (int ks = 0; ks < 2; ++ks) {
    bf16x8 af[2];
#pragma unroll
    for (int mi = 0; mi < 2; ++mi)
      af[mi] = *(const bf16x8*)(As + (wm + mi * 16 + fr) * 72 + ks * 32 + q * 8);
#pragma unroll
    for (int ni = 0; ni < 10; ++ni) {
      bf16x8 bw = *(const bf16x8*)(Ws + (ni * 16 + fr) * 72 + ks * 32 + q * 8);
      acc[0][ni] = mfma16(af[0], bw, acc[0][ni]);
      acc[1][ni] = mfma16(af[1], bw, acc[1][ni]);
    }
  }
#pragma unroll
  for (int mi = 0; mi < 2; ++mi)
#pragma unroll
    for (int ni = 0; ni < 10; ++ni) {
      int pl = wm + mi * 16 + q * 4;
      int co = ni * 16 + fr;
      float b = (co < 32) ? bia[co] : 0.f;
      short* dst;
      if (co < 32) {
        short* dd = (co < 8) ? QT : (co < 16) ? KT : (co < 24) ? QF : KF;
        dst = dd + ((size_t)(n * 8 + (co & 7))) * HW;
      } else if (co < 96) {
        dst = Vt + ((size_t)(n * 64 + (co - 32))) * HW;
      } else {
        dst = Vf + ((size_t)(n * 64 + (co - 96))) * HW;
      }
      s16x4 sv;
#pragma unroll
      for (int r = 0; r < 4; ++r) sv[r] = (short)f2bf(acc[mi][ni][r] + b);
      *(s16x4*)(dst + p0 + pl) = sv;
    }
}

// ---------------------------------------------------------------------------
// In-place 512x512 bf16 transpose of one plane, via 64x64 tile pairs.
// ---------------------------------------------------------------------------
__global__ __launch_bounds__(256, 4) void trans_k(short* __restrict__ V) {
  __shared__ short La[64][72];
  __shared__ short Lb[64][72];
  short* p = V + (size_t)blockIdx.y * HW;
  int b = blockIdx.x;
  int ti = 0;
  while (b >= 8 - ti) { b -= 8 - ti; ++ti; }
  int tj = ti + b;
  int tid = threadIdx.x;
  int hl = tid >> 4, wl = (tid & 15) * 4;
#pragma unroll
  for (int it = 0; it < 4; ++it) {
    int r = hl + it * 16;
    s16x4 va = *(const s16x4*)(p + (size_t)(ti * 64 + r) * 512 + tj * 64 + wl);
    La[wl + 0][r] = va[0]; La[wl + 1][r] = va[1];
    La[wl + 2][r] = va[2]; La[wl + 3][r] = va[3];
    if (ti != tj) {
      s16x4 vb = *(const s16x4*)(p + (size_t)(tj * 64 + r) * 512 + ti * 64 + wl);
      Lb[wl + 0][r] = vb[0]; Lb[wl + 1][r] = vb[1];
      Lb[wl + 2][r] = vb[2]; Lb[wl + 3][r] = vb[3];
    }
  }
  __syncthreads();
#pragma unroll
  for (int it = 0; it < 4; ++it) {
    int c = hl + it * 16;
    *(s16x4*)(p + (size_t)(tj * 64 + c) * 512 + ti * 64 + wl) =
        *(const s16x4*)(&La[c][wl]);
    if (ti != tj)
      *(s16x4*)(p + (size_t)(ti * 64 + c) * 512 + tj * 64 + wl) =
          *(const s16x4*)(&Lb[c][wl]);
  }
}

// ---------------------------------------------------------------------------
// Async GEMM, double-buffered: C[m][n] = sum_k A[m][k]*B[n][k], K=512, ld=512,
// both operands K-contiguous bf16. 128x128 tile, BK=32, 2x[128][32] LDS per
// operand. Stage(t+1) issued BEFORE compute(t) so the compiler's vmcnt(0)
// drain at the barrier lands after ~8 ds_read + 16 MFMA of covering work.
// ---------------------------------------------------------------------------
template<bool OBF>
__global__ __launch_bounds__(256, 4) void gemm_a(
    const short* __restrict__ A0, long az, int zshA,
    const short* __restrict__ B0, long bz, int zshB,
    void* __restrict__ C0, long cz) {
  __shared__ __align__(16) short As[2][128 * 32];
  __shared__ __align__(16) short Bs[2][128 * 32];
  int tid = threadIdx.x;
  int z = blockIdx.z;
  int m0g = blockIdx.y * 128, n0g = blockIdx.x * 128;
  const short* Abz = A0 + (size_t)(z >> zshA) * (size_t)az;
  const short* Bbz = B0 + (size_t)(z >> zshB) * (size_t)bz;
  int lane = tid & 63, wv = tid >> 6;
  int wm = (wv >> 1) * 64, wn = (wv & 1) * 64;
  int fr = lane & 15, q = lane >> 4;

  int srow = lane >> 2;         // 0..15
  int sch = (lane & 3) * 8;     // short offset within row
  const short* ga0 = Abz + (size_t)(m0g + wv * 32 + srow) * 512 + sch;
  const short* gb0 = Bbz + (size_t)(n0g + wv * 32 + srow) * 512 + sch;
  int lofs = (wv * 32) * 32;

  f32x4 acc[4][4];
#pragma unroll
  for (int mi = 0; mi < 4; ++mi)
#pragma unroll
    for (int ni = 0; ni < 4; ++ni) acc[mi][ni] = (f32x4){0.f, 0.f, 0.f, 0.f};

  // prologue: stage tile 0 into buffer 0
  gl_lds16(ga0, As[0] + lofs);
  gl_lds16(ga0 + 16 * 512, As[0] + lofs + 16 * 32);
  gl_lds16(gb0, Bs[0] + lofs);
  gl_lds16(gb0 + 16 * 512, Bs[0] + lofs + 16 * 32);
  __syncthreads();

#pragma unroll 2
  for (int s = 0; s < 16; ++s) {
    int p = s & 1;
    if (s < 15) {
      const short* ga = ga0 + (s + 1) * 32;
      const short* gb = gb0 + (s + 1) * 32;
      gl_lds16(ga, As[p ^ 1] + lofs);
      gl_lds16(ga + 16 * 512, As[p ^ 1] + lofs + 16 * 32);
      gl_lds16(gb, Bs[p ^ 1] + lofs);
      gl_lds16(gb + 16 * 512, Bs[p ^ 1] + lofs + 16 * 32);
    }
    bf16x8 af[4], bg[4];
#pragma unroll
    for (int mi = 0; mi < 4; ++mi)
      af[mi] = *(const bf16x8*)(As[p] + (wm + mi * 16 + fr) * 32 + q * 8);
#pragma unroll
    for (int ni = 0; ni < 4; ++ni)
      bg[ni] = *(const bf16x8*)(Bs[p] + (wn + ni * 16 + fr) * 32 + q * 8);
#pragma unroll
    for (int mi = 0; mi < 4; ++mi)
#pragma unroll
      for (int ni = 0; ni < 4; ++ni)
        acc[mi][ni] = mfma16(af[mi], bg[ni], acc[mi][ni]);
    __syncthreads();
  }

  size_t coff = (size_t)z * (size_t)cz;
#pragma unroll
  for (int mi = 0; mi < 4; ++mi)
#pragma unroll
    for (int ni = 0; ni < 4; ++ni) {
      int row = m0g + wm + mi * 16 + q * 4;
      int col = n0g + wn + ni * 16 + fr;
#pragma unroll
      for (int r = 0; r < 4; ++r) {
        float v = acc[mi][ni][r];
        if constexpr (OBF) {
          ((short*)C0)[coff + (size_t)(row + r) * LDIM + col] = (short)f2bf(v);
        } else {
          ((float*)C0)[coff + (size_t)(row + r) * LDIM + col] = v;
        }
      }
    }
}

// ---------------------------------------------------------------------------
// energy_f GEMM: both operands M-contiguous (k-strided) bf16; padded LDS,
// register transpose staging. C fp32.
// ---------------------------------------------------------------------------
__global__ __launch_bounds__(256, 2) void gemm_t(
    const short* __restrict__ A0, long az,
    const short* __restrict__ B0, long bz,
    float* __restrict__ C0, long cz) {
  __shared__ __align__(16) short As[128 * 40];
  __shared__ __align__(16) short Bs[128 * 40];
  int tid = threadIdx.x;
  int z = blockIdx.z;
  int m0g = blockIdx.y * 128, n0g = blockIdx.x * 128;
  const short* Abz = A0 + (size_t)z * (size_t)az;
  const short* Bbz = B0 + (size_t)z * (size_t)bz;
  int lane = tid & 63, wv = tid >> 6;
  int wm = (wv >> 1) * 64, wn = (wv & 1) * 64;
  int fr = lane & 15, q = lane >> 4;
  int mp = (tid & 63) * 2, k0 = (tid >> 6) * 8;

  f32x4 acc[4][4];
#pragma unroll
  for (int mi = 0; mi < 4; ++mi)
#pragma unroll
    for (int ni = 0; ni < 4; ++ni) acc[mi][ni] = (f32x4){0.f, 0.f, 0.f, 0.f};

  for (int kk = 0; kk < 512; kk += 32) {
    {
      const short* s = Abz + (size_t)(kk + k0) * 512 + m0g + mp;
      s16x8 c0, c1;
#pragma unroll
      for (int j = 0; j < 8; ++j) {
        unsigned v = *(const unsigned*)(s + (size_t)j * 512);
        c0[j] = (short)(v & 0xffffu);
        c1[j] = (short)(v >> 16);
      }
      *(s16x8*)(As + mp * 40 + k0) = c0;
      *(s16x8*)(As + (mp + 1) * 40 + k0) = c1;
    }
    {
      const short* s = Bbz + (size_t)(kk + k0) * 512 + n0g + mp;
      s16x8 c0, c1;
#pragma unroll
      for (int j = 0; j < 8; ++j) {
        unsigned v = *(const unsigned*)(s + (size_t)j * 512);
        c0[j] = (short)(v & 0xffffu);
        c1[j] = (short)(v >> 16);
      }
      *(s16x8*)(Bs + mp * 40 + k0) = c0;
      *(s16x8*)(Bs + (mp + 1) * 40 + k0) = c1;
    }
    __syncthreads();
    bf16x8 af[4], bg[4];
#pragma unroll
    for (int mi = 0; mi < 4; ++mi)
      af[mi] = *(const bf16x8*)(As + (wm + mi * 16 + fr) * 40 + q * 8);
#pragma unroll
    for (int ni = 0; ni < 4; ++ni)
      bg[ni] = *(const bf16x8*)(Bs + (wn + ni * 16 + fr) * 40 + q * 8);
#pragma unroll
    for (int mi = 0; mi < 4; ++mi)
#pragma unroll
      for (int ni = 0; ni < 4; ++ni)
        acc[mi][ni] = mfma16(af[mi], bg[ni], acc[mi][ni]);
    __syncthreads();
  }

  size_t coff = (size_t)z * (size_t)cz;
#pragma unroll
  for (int mi = 0; mi < 4; ++mi)
#pragma unroll
    for (int ni = 0; ni < 4; ++ni) {
      int row = m0g + wm + mi * 16 + q * 4;
      int col = n0g + wn + ni * 16 + fr;
#pragma unroll
      for (int r = 0; r < 4; ++r)
        C0[coff + (size_t)(row + r) * LDIM + col] = acc[mi][ni][r];
    }
}

// ---------------------------------------------------------------------------
// Row softmax over 512 logits with 8-way split-K partial sum; output scaled
// by gamma (folds the branch gamma into the attention weights).
// ---------------------------------------------------------------------------
__global__ __launch_bounds__(256, 4) void softmax8_k(const float* __restrict__ Ep,
                                                     const float* __restrict__ gp,
                                                     short* __restrict__ A) {
  int tid = threadIdx.x;
  int lane = tid & 63, wv = tid >> 6;
  int row = blockIdx.x * 4 + wv;        // n*512 + r
  int n = row >> 9, h = row & 511;
  const float* base = Ep + (size_t)(n * 8) * HW + (size_t)h * 512 + lane * 8;
  float v[8] = {0.f, 0.f, 0.f, 0.f, 0.f, 0.f, 0.f, 0.f};
#pragma unroll
  for (int cc = 0; cc < 8; ++cc) {
    const float* e = base + (size_t)cc * HW;
    float4 a = *(const float4*)e;
    float4 b = *(const float4*)(e + 4);
    v[0] += a.x; v[1] += a.y; v[2] += a.z; v[3] += a.w;
    v[4] += b.x; v[5] += b.y; v[6] += b.z; v[7] += b.w;
  }
  float m = v[0];
#pragma unroll
  for (int j = 1; j < 8; ++j) m = fmaxf(m, v[j]);
#pragma unroll
  for (int off = 32; off >= 1; off >>= 1) m = fmaxf(m, __shfl_xor(m, off));
  float s = 0.f;
#pragma unroll
  for (int j = 0; j < 8; ++j) {
    v[j] = __expf(v[j] - m);
    s += v[j];
  }
#pragma unroll
  for (int off = 32; off >= 1; off >>= 1) s += __shfl_xor(s, off);
  float sc = gp[0] / s;
  s16x8 o;
#pragma unroll
  for (int j = 0; j < 8; ++j) o[j] = (short)f2bf(v[j] * sc);
  *(s16x8*)(A + (size_t)row * LDIM + lane * 8) = o;
}

// ---------------------------------------------------------------------------
// Fused dual-branch attention GEMM as ONE K=1024 GEMM, double-buffered LDS,
// XOR-swizzled chunks (store side via pre-swizzled GLOBAL source since
// global_load_lds writes linearly; read side via swizzled chunk offset).
//   t<16 :  A = At[n] (rows h), B = VtT[z] (rows w)      K-contig
//   t>=16:  A = Vf[z] (rows h), B = Af[n] (rows w)       K-contig
//   out[z][h][w] = 3*x[z][h][w] + acc + (gt*tvb[o] + gf*fvb[o])
// 1D grid, bijective XCD-aware decode (B-panel reused within one XCD's L2).
// ---------------------------------------------------------------------------
__global__ __launch_bounds__(256, 4) void gemm_tf(
    const short* __restrict__ At, const short* __restrict__ VtT,
    const short* __restrict__ Vf, const short* __restrict__ Af,
    const float* __restrict__ x,
    const float* __restrict__ tvb, const float* __restrict__ fvb,
    const float* __restrict__ tg, const float* __restrict__ fg,
    float* __restrict__ out, int Z) {
  __shared__ __align__(16) short As[2][128 * 32];
  __shared__ __align__(16) short Bs[2][128 * 32];
  int tid = threadIdx.x;
  // bijective decode of f -> (yt, nt, z); Z is even
  int f = blockIdx.x;
  int xcd = f & 7, j = f >> 3;
  int yt = j & 3;
  int pid = xcd * (Z >> 1) + (j >> 2);
  int nt = pid & 3, z = pid >> 2;
  int n = z >> 6, o = z & 63;
  int m0g = yt * 128, n0g = nt * 128;

  int lane = tid & 63, wv = tid >> 6;
  int wm = (wv >> 1) * 64, wn = (wv & 1) * 64;
  int fr = lane & 15, q = lane >> 4;
  // store-side swizzle: physical chunk (lane&3) holds logical chunk
  // (lane&3)^((row>>1)&3); row = wv*32 + half*16 + (lane>>2)
  int srow = lane >> 2;
  int sch = ((lane & 3) ^ ((lane >> 3) & 3)) * 8;
  int lofs = (wv * 32) * 32;
  // read-side swizzle: logical chunk q lives at physical chunk q^((fr>>1)&3)
  int sq = (q ^ ((fr >> 1) & 3)) * 8;

  const short* g1a = At + (size_t)n * HW + (size_t)(m0g + wv * 32 + srow) * 512 + sch;
  const short* g1b = VtT + (size_t)z * HW + (size_t)(n0g + wv * 32 + srow) * 512 + sch;
  const short* g2a = Vf + (size_t)z * HW + (size_t)(m0g + wv * 32 + srow) * 512 + sch;
  const short* g2b = Af + (size_t)n * HW + (size_t)(n0g + wv * 32 + srow) * 512 + sch;

  f32x4 acc[4][4];
#pragma unroll
  for (int mi = 0; mi < 4; ++mi)
#pragma unroll
    for (int ni = 0; ni < 4; ++ni) acc[mi][ni] = (f32x4){0.f, 0.f, 0.f, 0.f};

  // prologue: stage K-tile 0 into buffer 0
  gl_lds16(g1a, As[0] + lofs);
  gl_lds16(g1a + 16 * 512, As[0] + lofs + 16 * 32);
  gl_lds16(g1b, Bs[0] + lofs);
  gl_lds16(g1b + 16 * 512, Bs[0] + lofs + 16 * 32);
  __syncthreads();

#pragma unroll 2
  for (int s = 0; s < 32; ++s) {
    int p = s & 1;
    if (s < 31) {
      int t = s + 1;
      const short* ga = (t < 16) ? g1a + t * 32 : g2a + (t - 16) * 32;
      const short* gb = (t < 16) ? g1b + t * 32 : g2b + (t - 16) * 32;
      gl_lds16(ga, As[p ^ 1] + lofs);
      gl_lds16(ga + 16 * 512, As[p ^ 1] + lofs + 16 * 32);
      gl_lds16(gb, Bs[p ^ 1] + lofs);
      gl_lds16(gb + 16 * 512, Bs[p ^ 1] + lofs + 16 * 32);
    }
    bf16x8 af[4], bg[4];
#pragma unroll
    for (int mi = 0; mi < 4; ++mi)
      af[mi] = *(const bf16x8*)(As[p] + (wm + mi * 16 + fr) * 32 + sq);
#pragma unroll
    for (int ni = 0; ni < 4; ++ni)
      bg[ni] = *(const bf16x8*)(Bs[p] + (wn + ni * 16 + fr) * 32 + sq);
#pragma unroll
    for (int mi = 0; mi < 4; ++mi)
#pragma unroll
      for (int ni = 0; ni < 4; ++ni)
        acc[mi][ni] = mfma16(af[mi], bg[ni], acc[mi][ni]);
    __syncthreads();
  }

  float cb = tg[0] * tvb[o] + fg[0] * fvb[o];
  size_t zoff = (size_t)z * HW;
#pragma unroll
  for (int mi = 0; mi < 4; ++mi)
#pragma unroll
    for (int ni = 0; ni < 4; ++ni) {
      int row = m0g + wm + mi * 16 + q * 4;
      int col = n0g + wn + ni * 16 + fr;
#pragma unroll
      for (int r = 0; r < 4; ++r) {
        size_t idx = zoff + (size_t)(row + r) * LDIM + col;
        out[idx] = 3.f * x[idx] + acc[mi][ni][r] + cb;
      }
    }
}

// ---------------------------------------------------------------------------
extern "C" void kernel_launch(void* const* d_in, const int* in_sizes, int n_in,
                              void* d_out, int out_size, void* d_ws, size_t ws_size,
                              hipStream_t stream) {
  (void)in_sizes; (void)n_in; (void)out_size;
  const float* x   = (const float*)d_in[0];
  const float* tqw = (const float*)d_in[1];
  const float* tqb = (const float*)d_in[2];
  const float* tkw = (const float*)d_in[3];
  const float* tkb = (const float*)d_in[4];
  const float* tvw = (const float*)d_in[5];
  const float* tvb = (const float*)d_in[6];
  const float* tg  = (const float*)d_in[7];
  const float* fqw = (const float*)d_in[8];
  const float* fqb = (const float*)d_in[9];
  const float* fkw = (const float*)d_in[10];
  const float* fkb = (const float*)d_in[11];
  const float* fvw = (const float*)d_in[12];
  const float* fvb = (const float*)d_in[13];
  const float* fg  = (const float*)d_in[14];
  float* out = (float*)d_out;

  // per-batch: Vt 32M + Vf 32M + QK 16M = 80 MiB
  const size_t per_n = ((size_t)64 * HW * 2) * 2     // Vt, Vf
                     + ((size_t)8 * HW * 2) * 4;     // QT,KT,QF,KF
  int nb = (ws_size >= 4 * per_n) ? 4
         : (ws_size >= 2 * per_n) ? 2 : 1;

  char* wb = (char*)d_ws;
  size_t sz_v  = (size_t)nb * 64 * HW * 2;
  size_t sz_qk = (size_t)nb * 8 * HW * 2;
  short* Vt = (short*)(wb);                  // transposed in place -> VtT
  short* Vf = (short*)(wb + sz_v);
  short* QT = (short*)(wb + 2 * sz_v);
  short* KT = (short*)(wb + 2 * sz_v + sz_qk);
  short* QF = (short*)(wb + 2 * sz_v + 2 * sz_qk);
  short* KF = (short*)(wb + 2 * sz_v + 3 * sz_qk);
  short* At = QT;   // alias: QT dead once energy_t gemm has run
  short* Af = QF;   // alias: QF dead once energy_f gemm has run

  for (int n0 = 0; n0 < 4; n0 += nb) {
    const float* xn = x + (size_t)n0 * 64 * HW;
    float* outn = out + (size_t)n0 * 64 * HW;
    // energy partials live in the (not-yet-written) output buffer:
    float* EbT = outn;
    float* EbF = outn + (size_t)nb * 8 * HW;

    conv_all_k<<<dim3(nb * 2048), dim3(256), 0, stream>>>(
        xn, tqw, tqb, tkw, tkb, fqw, fqb, fkw, fkb, tvw, fvw,
        QT, KT, QF, KF, Vt, Vf);
    trans_k<<<dim3(36, nb * 64), dim3(256), 0, stream>>>(Vt);
    // energy_t partials: per z=(n*8+c), Qt[z] @ Kt[z]^T (K=512)
    gemm_a<false><<<dim3(4, 4, nb * 8), dim3(256), 0, stream>>>(
        QT, (long)HW, 0, KT, (long)HW, 0, EbT, (long)HW);
    softmax8_k<<<dim3(nb * 128), dim3(256), 0, stream>>>(EbT, tg, At);
    // energy_f partials: per z, E[w][v] = sum_h Qf[z][h][w]*Kf[z][h][v]
    gemm_t<<<dim3(4, 4, nb * 8), dim3(256), 0, stream>>>(
        QF, (long)HW, KF, (long)HW, EbF, (long)HW);
    softmax8_k<<<dim3(nb * 128), dim3(256), 0, stream>>>(EbF, fg, Af);
    // fused dual-branch attention + residual + bias -> final output
    gemm_tf<<<dim3(16 * nb * 64), dim3(256), 0, stream>>>(
        At, Vt, Vf, Af, xn, tvb, fvb, tg, fg, outn, nb * 64);
  }
}